// Round 1
// baseline (344.112 us; speedup 1.0000x reference)
//
#include <hip/hip_runtime.h>
#include <stdint.h>

// ProposalLayerSoft: 3x3x3 NMS + per-batch top-10 + coord epilogue.
// Input:  d_in[0] = root_cubes f32 [B=32, X=128, Y=128, Z=64]
// Output: d_out   = f32 [B, 10, 5] = (x,y,z, valid-1, score)
// ws: 32*40*10*8 = 102,400 bytes of per-block top-10 keys.
//
// Round-10 slab (y-coalesced, lane = zq*16+yi, 16-z stripe, x-sweep) with
// a ROLLED t-loop. Theory: every fully-unrolled variant (rounds 5-11)
// produced a 15-30 KB hot body that thrashes the 32 KB I$ -- explaining
// ~75 us walls with ALL pipes <30% busy, invariant to memory strategy.
// Rolled body ~3 KB. State compression: instead of 3 zm planes keep
// pm[j] = max(zm(x-1), zm(x)) and zmLast[j] = zm(x) -- the 27-max is
// m27 = max(pm, zm(x+1), y-neighbors via DPP). 5x16 live floats.
//   z: in-register max3 + 2 shuffles (lane+-16 stripe boundary)
//   y: v_mov_dpp row_shl/shr:1 (row-edge fill only hits yi=0/15 halo)
//   x: rolled sweep, prefetch plane x+2 into vT at loop top
// Peaks: ballot+mbcnt compacted append to per-wave LDS list (no atomics).
//
// THIS ROUND: __launch_bounds__(256,4) -> (256,6). Tail-quantization fix:
// grid is 1280 blocks; at 4 blocks/CU residency that is a 1024-block main
// phase (occ 50%) + 256-block tail (occ 12.5%) -> measured 29% avg, 2x
// makespan. Rolled kernel is 60 VGPRs, far under the 85-VGPR cap of
// 6 waves/SIMD (the round-6/9 scratch/spill notes were for the unrolled
// high-pressure variants). 6 blocks/CU = 1536 capacity -> all 1280
// co-resident, no tail. LDS 6 x 16.9 KB = 101 KB < 160 KB.

#define TPB 256
#define NK 10
#define TY 10                    // y tiles, 14 interior columns each
#define BLOCKS_PER_B (4 * TY)    // grid.y=4 seg-packs x 10 ty = 40
#define WCAP 512                 // per-wave cand cap (mean ~265, +15 sigma)
typedef unsigned long long u64;

__device__ __forceinline__ u64 bfly_max_u64(u64 v) {
#pragma unroll
  for (int off = 1; off < 64; off <<= 1) {
    u64 o = __shfl_xor(v, off, 64);
    v = (o > v) ? o : v;
  }
  return v;
}

// DPP row shifts within 16-lane rows; bound_ctrl=1 -> 0.0f fill at row
// edges (only yi=0/15 halo lanes, never emitted).
__device__ __forceinline__ float dpp_nbr_a(float v) {  // one y-neighbor
  return __int_as_float(__builtin_amdgcn_update_dpp(
      0, __float_as_int(v), 0x101, 0xF, 0xF, true));   // row_shl:1
}
__device__ __forceinline__ float dpp_nbr_b(float v) {  // other y-neighbor
  return __int_as_float(__builtin_amdgcn_update_dpp(
      0, __float_as_int(v), 0x111, 0xF, 0xF, true));   // row_shr:1
}

__global__ __launch_bounds__(TPB, 6) void peaks_topk(
    const float* __restrict__ in, u64* __restrict__ part) {
  __shared__ u64 cand[4][WCAP];  // 16 KB
  __shared__ u64 wtop[4 * NK];
  const int tid = threadIdx.x;
  const int w = tid >> 6, lane = tid & 63;
  const int yi = lane & 15, zq = lane >> 4;
  const int ty = blockIdx.x, b = blockIdx.z;
  const int seg = blockIdx.y * 4 + w;        // 0..15, 8 x-steps each
  const int y0 = ty * 14 - 1;
  const int gy = y0 + yi;
  const int cy = min(127, max(0, gy));       // clamp == dup col: max-safe
  const int x0 = seg * 8;
  const bool emit_ok = (yi >= 1) && (yi <= 14) && (gy <= 127);
  const float* __restrict__ col =
      in + ((size_t)b << 20) + ((size_t)cy << 6) + (zq << 4);

  int wcnt = 0;  // wave-uniform candidate count (scalar)
  float vC[16], vN[16], vT[16], pm[16], zmLast[16], zmN[16];

  auto loadv = [&](int x, float* v) {
    const int cx = min(127, max(0, x));
    const float4* p = (const float4*)(col + ((size_t)cx << 13));
    float4 a = p[0], bb = p[1], c = p[2], d = p[3];
    v[0] = a.x;  v[1] = a.y;  v[2] = a.z;  v[3] = a.w;
    v[4] = bb.x; v[5] = bb.y; v[6] = bb.z; v[7] = bb.w;
    v[8] = c.x;  v[9] = c.y;  v[10] = c.z; v[11] = c.w;
    v[12] = d.x; v[13] = d.y; v[14] = d.z; v[15] = d.w;
  };
  // z-stage: stripe-internal max3; boundaries via 2 shuffles (lane+-16 =
  // same yi, zq+-1); zq edges (z=-1 / z=64) forced to -inf.
  auto zmcalc = [&](const float* v, float* zm) {
    float vl = __shfl_up(v[15], 16, 64);
    float vr = __shfl_down(v[0], 16, 64);
    vl = (zq == 0) ? -1e30f : vl;
    vr = (zq == 3) ? -1e30f : vr;
    zm[0] = fmaxf(vl, fmaxf(v[0], v[1]));
#pragma unroll
    for (int j = 1; j < 15; ++j)
      zm[j] = fmaxf(v[j - 1], fmaxf(v[j], v[j + 1]));
    zm[15] = fmaxf(v[14], fmaxf(v[15], vr));
  };

  // Prologue: pm = max(zm(x0-1), zm(x0)); zmLast = zm(x0);
  //           vC = v(x0); vN = v(x0+1).
  loadv(x0 - 1, vT);
  zmcalc(vT, zmN);                // zm(x0-1) in zmN temp
  loadv(x0, vC);
  zmcalc(vC, zmLast);             // zm(x0)
#pragma unroll
  for (int j = 0; j < 16; ++j) pm[j] = fmaxf(zmN[j], zmLast[j]);
  loadv(x0 + 1, vN);

#pragma unroll 1
  for (int t = 0; t < 8; ++t) {
    const int x = x0 + t;
    if (t < 7) loadv(x + 2, vT);  // prefetch one plane ahead
    zmcalc(vN, zmN);              // zm(x+1)
#pragma unroll
    for (int j = 0; j < 16; ++j) {
      float xm = fmaxf(pm[j], zmN[j]);     // max over zm(x-1),zm(x),zm(x+1)
      float l = dpp_nbr_a(xm);             // y-neighbors via DPP
      float r = dpp_nbr_b(xm);
      float m27 = fmaxf(xm, fmaxf(l, r));
      float v = vC[j];
      const bool pred = emit_ok && (v >= m27);  // v == 27-max (self-incl.)
      u64 mask = __ballot(pred);
      if (pred) {
        unsigned g = ((unsigned)x << 13) | ((unsigned)gy << 6) |
                     (unsigned)((zq << 4) + j);
        u64 key = ((u64)__float_as_uint(v) << 32) | (u64)(unsigned)(~g);
        int ofs = __builtin_amdgcn_mbcnt_hi(
            (unsigned)(mask >> 32),
            __builtin_amdgcn_mbcnt_lo((unsigned)mask, 0));
        int slot = wcnt + ofs;
        if (slot < WCAP) cand[w][slot] = key;
      }
      wcnt += (int)__popcll(mask);
    }
    // rotate state (fixed-index, stays in registers)
#pragma unroll
    for (int j = 0; j < 16; ++j) {
      pm[j] = fmaxf(zmLast[j], zmN[j]);
      zmLast[j] = zmN[j];
      vC[j] = vN[j];
      vN[j] = vT[j];
    }
  }

  // ---- wave top-10 from LDS list (regs + butterfly, no barriers) ----
  __builtin_amdgcn_s_waitcnt(0);  // drain own-wave LDS writes
  const int count = min(wcnt, WCAP);
  u64 c[WCAP / 64];
#pragma unroll
  for (int i = 0; i < WCAP / 64; ++i) {
    int idx = lane + (i << 6);
    c[i] = (idx < count) ? cand[w][idx] : 0;
  }
  u64 mine = 0;
#pragma unroll 1
  for (int r = 0; r < NK; ++r) {
    u64 best = c[0];
#pragma unroll
    for (int i = 1; i < WCAP / 64; ++i) best = (c[i] > best) ? c[i] : best;
    u64 m = bfly_max_u64(best);
    if (m != 0 && best == m) {  // unique keys: only owner lane matches
#pragma unroll
      for (int i = 0; i < WCAP / 64; ++i)
        if (c[i] == m) c[i] = 0;
    }
    if (lane == r) mine = m;
  }
  if (lane < NK) wtop[w * NK + lane] = mine;
  __syncthreads();

  // ---- block merge 40 -> 10 (wave 0), one barrier total ----
  if (w == 0) {
    u64 c0 = (lane < 4 * NK) ? wtop[lane] : 0;
    u64 mv = 0;
#pragma unroll 1
    for (int r = 0; r < NK; ++r) {
      u64 m = bfly_max_u64(c0);
      if (m != 0 && c0 == m) c0 = 0;
      if (lane == r) mv = m;
    }
    if (lane < NK) {
      const int bi = blockIdx.y * TY + ty;  // 0..39 within batch
      part[((size_t)b * BLOCKS_PER_B + bi) * NK + lane] = mv;
    }
  }
}

// One wave per batch: 400 keys -> 7 regs/lane -> 10 butterfly rounds.
// Zero barriers, zero LDS.
__global__ __launch_bounds__(64) void final_select(
    const u64* __restrict__ part, float* __restrict__ out) {
  const int lane = threadIdx.x & 63;
  const int b = blockIdx.x;
  const int NKEY = BLOCKS_PER_B * NK;  // 400

  const u64* __restrict__ src = part + (size_t)b * NKEY;
  u64 c[7];
#pragma unroll
  for (int i = 0; i < 7; ++i) {
    int idx = lane + (i << 6);
    c[i] = (idx < NKEY) ? src[idx] : 0;
  }
  u64 mine = 0;
#pragma unroll 1
  for (int r = 0; r < NK; ++r) {
    u64 best = c[0];
#pragma unroll
    for (int i = 1; i < 7; ++i) best = (c[i] > best) ? c[i] : best;
    u64 m = bfly_max_u64(best);
    if (m != 0 && best == m) {
#pragma unroll
      for (int i = 0; i < 7; ++i)
        if (c[i] == m) c[i] = 0;
    }
    if (lane == r) mine = m;
  }
  if (lane < NK) {
    float val = 0.0f;
    unsigned g = 0u;
    if (mine != 0) {
      val = __uint_as_float((unsigned)(mine >> 32));
      g = ~((unsigned)mine);
    }
    float fx = (float)(g >> 13) * (8000.0f / 127.0f) - 4000.0f;
    float fy = (float)((g >> 6) & 127u) * (8000.0f / 127.0f) - 4000.0f;
    float fz = (float)(g & 63u) * (2000.0f / 63.0f) - 700.0f;
    float conf = (val > 0.3f) ? 0.0f : -1.0f;
    float* o = out + ((size_t)b * NK + lane) * 5;
    o[0] = fx; o[1] = fy; o[2] = fz; o[3] = conf; o[4] = val;
  }
}

extern "C" void kernel_launch(void* const* d_in, const int* in_sizes, int n_in,
                              void* d_out, int out_size, void* d_ws, size_t ws_size,
                              hipStream_t stream) {
  const float* in = (const float*)d_in[0];
  float* out = (float*)d_out;
  u64* part = (u64*)d_ws;  // 102,400 B used

  const int B = in_sizes[0] >> 20;  // 128*128*64 = 2^20 elements per batch
  dim3 gridA(TY, 4, (unsigned)B);
  peaks_topk<<<gridA, dim3(TPB), 0, stream>>>(in, part);
  final_select<<<dim3((unsigned)B), dim3(64), 0, stream>>>(part, out);
}

// Round 2
// 222.348 us; speedup vs baseline: 1.5476x; 1.5476x over previous
//
#include <hip/hip_runtime.h>
#include <stdint.h>

// ProposalLayerSoft: 3x3x3 NMS + per-batch top-10 + coord epilogue.
// Input:  d_in[0] = root_cubes f32 [B=32, X=128, Y=128, Z=64]
// Output: d_out   = f32 [B, 10, 5] = (x,y,z, valid-1, score)
// ws: 32*40*10*8 = 102,400 bytes of per-block top-10 keys.
//
// THIS ROUND: 8-z-per-lane slab to fit the 48-VGPR budget of
// __launch_bounds__(256,5). Model (fits r0/r1/r6/r9 evidence): compiler
// VGPR cap = 256/min_waves (gran 8): 4->64, 5->48, 6->40(spilled r1);
// HW capacity = floor(256/vgpr8) blocks/CU. Round-0 (VGPR 60->64) ran at
// capacity 4 -> 1280 blocks = two phases (occ 29%, VALUBusy 35%, 2T=78us).
// Capacity 5 x 256 CU = 1280 = grid -> SINGLE phase, makespan T.
// 16-z layout needs 4 planes x 16 = 64 carried floats -- can't fit 48.
// 8-z layout: carried pm/zmLast/vC/vN = 32 + halos/temps ~= 44-48. Wave
// covers 16 x-steps x 14 y x 32 z (same 7168 voxels -> WCAP stats same);
// block = 2 segs x 2 z-halves; grid/part layout unchanged.
//   z: in-register max3; stripe bounds via lane+-16 shuffles; cross-wave
//      halo (z=31/32) via 2 clamped scalar loads per plane.
//   y: v_mov_dpp row_shl/shr:1 as before.
//   x: rolled 16-step sweep, 2-array rotation (no prefetch array -- the
//      per-iter load stall is TLP-hidden at 5 resident waves/SIMD).
// DO NOT raise min_waves past 5 without cutting state: cap 6 = 40 VGPR
// spilled 580 MB (round 1). 16-z + bound 5 also spills (round 9).

#define TPB 256
#define NK 10
#define TY 10                    // y tiles, 14 interior columns each
#define BLOCKS_PER_B (4 * TY)    // grid.y=4 packs x 10 ty = 40
#define WCAP 512                 // per-wave cand cap (mean ~265, +15 sigma)
typedef unsigned long long u64;

__device__ __forceinline__ u64 bfly_max_u64(u64 v) {
#pragma unroll
  for (int off = 1; off < 64; off <<= 1) {
    u64 o = __shfl_xor(v, off, 64);
    v = (o > v) ? o : v;
  }
  return v;
}

// DPP row shifts within 16-lane rows; bound_ctrl=1 -> 0.0f fill at row
// edges (only yi=0/15 halo lanes, never emitted).
__device__ __forceinline__ float dpp_nbr_a(float v) {  // one y-neighbor
  return __int_as_float(__builtin_amdgcn_update_dpp(
      0, __float_as_int(v), 0x101, 0xF, 0xF, true));   // row_shl:1
}
__device__ __forceinline__ float dpp_nbr_b(float v) {  // other y-neighbor
  return __int_as_float(__builtin_amdgcn_update_dpp(
      0, __float_as_int(v), 0x111, 0xF, 0xF, true));   // row_shr:1
}

__global__ __launch_bounds__(TPB, 5) void peaks_topk(
    const float* __restrict__ in, u64* __restrict__ part) {
  __shared__ u64 cand[4][WCAP];  // 16 KB
  __shared__ u64 wtop[4 * NK];
  const int tid = threadIdx.x;
  const int w = tid >> 6, lane = tid & 63;
  const int yi = lane & 15, zq = lane >> 4;
  const int ty = blockIdx.x, b = blockIdx.z;
  const int seg = blockIdx.y * 2 + (w >> 1);  // 0..7, 16 x-steps each
  const int zh = w & 1;                       // z half: 0 -> z 0..31, 1 -> 32..63
  const int y0 = ty * 14 - 1;
  const int gy = y0 + yi;
  const int cy = min(127, max(0, gy));        // clamp == dup col: max-safe
  const int x0 = seg << 4;
  const bool emit_ok = (yi >= 1) && (yi <= 14) && (gy <= 127);
  const int zoff = zh * 32 + (zq << 3);       // lane's z base in column
  const int zlo = max(0, zoff - 1);           // cross-wave z halo offsets
  const int zhi = min(63, zoff + 8);          // (clamped: OOB -> -inf select)
  const bool lo_inf = (zq == 0) && (zh == 0); // z = -1
  const bool hi_inf = (zq == 3) && (zh == 1); // z = 64
  const float* __restrict__ py = in + ((size_t)b << 20) + ((size_t)cy << 6);

  int wcnt = 0;  // wave-uniform candidate count (scalar)
  float pm[8], zmLast[8], vC[8], vN[8];

  auto loadv = [&](int x, float* v, float& lo, float& hi) {
    const int cx = min(127, max(0, x));       // x clamp = dup plane: max-safe
    const float* p = py + ((size_t)cx << 13);
    float4 a = *(const float4*)(p + zoff);
    float4 bb = *(const float4*)(p + zoff + 4);
    v[0] = a.x;  v[1] = a.y;  v[2] = a.z;  v[3] = a.w;
    v[4] = bb.x; v[5] = bb.y; v[6] = bb.z; v[7] = bb.w;
    lo = p[zlo];                              // used by zq==0 lanes
    hi = p[zhi];                              // used by zq==3 lanes
  };
  // z-stage max3 over 8-elem stripe; stripe bounds: lane+-16 shuffles for
  // in-wave quads, loaded halo scalar (or -inf at volume edge) otherwise.
  auto zmcalc = [&](const float* v, float lo, float hi, float* zm) {
    float vl = __shfl_up(v[7], 16, 64);
    float vr = __shfl_down(v[0], 16, 64);
    vl = (zq == 0) ? (lo_inf ? -1e30f : lo) : vl;
    vr = (zq == 3) ? (hi_inf ? -1e30f : hi) : vr;
    zm[0] = fmaxf(vl, fmaxf(v[0], v[1]));
#pragma unroll
    for (int j = 1; j < 7; ++j)
      zm[j] = fmaxf(v[j - 1], fmaxf(v[j], v[j + 1]));
    zm[7] = fmaxf(v[6], fmaxf(v[7], vr));
  };

  // Prologue: pm = max(zm(x0-1), zm(x0)); zmLast = zm(x0); vC = v(x0).
  {
    float t0, t1;
    loadv(x0 - 1, vN, t0, t1);
    zmcalc(vN, t0, t1, pm);        // pm holds zm(x0-1) temporarily
    loadv(x0, vC, t0, t1);
    zmcalc(vC, t0, t1, zmLast);    // zm(x0)
#pragma unroll
    for (int j = 0; j < 8; ++j) pm[j] = fmaxf(pm[j], zmLast[j]);
  }

#pragma unroll 1
  for (int t = 0; t < 16; ++t) {
    const int x = x0 + t;
    float lN, hN;
    loadv(x + 1, vN, lN, hN);      // plane x+1 (stall TLP-hidden)
    float vl = __shfl_up(vN[7], 16, 64);
    float vr = __shfl_down(vN[0], 16, 64);
    vl = (zq == 0) ? (lo_inf ? -1e30f : lN) : vl;
    vr = (zq == 3) ? (hi_inf ? -1e30f : hN) : vr;
#pragma unroll
    for (int j = 0; j < 8; ++j) {  // fused zm + rotate + emit (min live set)
      float a = (j == 0) ? vl : vN[j - 1];
      float c = (j == 7) ? vr : vN[j + 1];
      float zmn = fmaxf(a, fmaxf(vN[j], c));      // zm(x+1)[j]
      float xm = fmaxf(pm[j], zmn);               // max over 3 x-planes
      pm[j] = fmaxf(zmLast[j], zmn);              // rotate in place
      zmLast[j] = zmn;
      float l = dpp_nbr_a(xm);                    // y-neighbors via DPP
      float r = dpp_nbr_b(xm);
      float m27 = fmaxf(xm, fmaxf(l, r));
      float v = vC[j];
      const bool pred = emit_ok && (v >= m27);    // v == 27-max (self-incl.)
      u64 mask = __ballot(pred);
      if (pred) {
        unsigned g = ((unsigned)x << 13) | ((unsigned)gy << 6) |
                     (unsigned)(zoff + j);
        u64 key = ((u64)__float_as_uint(v) << 32) | (u64)(unsigned)(~g);
        int ofs = __builtin_amdgcn_mbcnt_hi(
            (unsigned)(mask >> 32),
            __builtin_amdgcn_mbcnt_lo((unsigned)mask, 0));
        int slot = wcnt + ofs;
        if (slot < WCAP) cand[w][slot] = key;
      }
      wcnt += (int)__popcll(mask);
    }
#pragma unroll
    for (int j = 0; j < 8; ++j) vC[j] = vN[j];    // rotate compare plane
  }

  // ---- wave top-10 from LDS list (regs + butterfly, no barriers) ----
  __builtin_amdgcn_s_waitcnt(0);  // drain own-wave LDS writes
  const int count = min(wcnt, WCAP);
  u64 c[WCAP / 64];
#pragma unroll
  for (int i = 0; i < WCAP / 64; ++i) {
    int idx = lane + (i << 6);
    c[i] = (idx < count) ? cand[w][idx] : 0;
  }
  u64 mine = 0;
#pragma unroll 1
  for (int r = 0; r < NK; ++r) {
    u64 best = c[0];
#pragma unroll
    for (int i = 1; i < WCAP / 64; ++i) best = (c[i] > best) ? c[i] : best;
    u64 m = bfly_max_u64(best);
    if (m != 0 && best == m) {  // unique keys: only owner lane matches
#pragma unroll
      for (int i = 0; i < WCAP / 64; ++i)
        if (c[i] == m) c[i] = 0;
    }
    if (lane == r) mine = m;
  }
  if (lane < NK) wtop[w * NK + lane] = mine;
  __syncthreads();

  // ---- block merge 40 -> 10 (wave 0), one barrier total ----
  if (w == 0) {
    u64 c0 = (lane < 4 * NK) ? wtop[lane] : 0;
    u64 mv = 0;
#pragma unroll 1
    for (int r = 0; r < NK; ++r) {
      u64 m = bfly_max_u64(c0);
      if (m != 0 && c0 == m) c0 = 0;
      if (lane == r) mv = m;
    }
    if (lane < NK) {
      const int bi = blockIdx.y * TY + ty;  // 0..39 within batch
      part[((size_t)b * BLOCKS_PER_B + bi) * NK + lane] = mv;
    }
  }
}

// One wave per batch: 400 keys -> 7 regs/lane -> 10 butterfly rounds.
// Zero barriers, zero LDS.
__global__ __launch_bounds__(64) void final_select(
    const u64* __restrict__ part, float* __restrict__ out) {
  const int lane = threadIdx.x & 63;
  const int b = blockIdx.x;
  const int NKEY = BLOCKS_PER_B * NK;  // 400

  const u64* __restrict__ src = part + (size_t)b * NKEY;
  u64 c[7];
#pragma unroll
  for (int i = 0; i < 7; ++i) {
    int idx = lane + (i << 6);
    c[i] = (idx < NKEY) ? src[idx] : 0;
  }
  u64 mine = 0;
#pragma unroll 1
  for (int r = 0; r < NK; ++r) {
    u64 best = c[0];
#pragma unroll
    for (int i = 1; i < 7; ++i) best = (c[i] > best) ? c[i] : best;
    u64 m = bfly_max_u64(best);
    if (m != 0 && best == m) {
#pragma unroll
      for (int i = 0; i < 7; ++i)
        if (c[i] == m) c[i] = 0;
    }
    if (lane == r) mine = m;
  }
  if (lane < NK) {
    float val = 0.0f;
    unsigned g = 0u;
    if (mine != 0) {
      val = __uint_as_float((unsigned)(mine >> 32));
      g = ~((unsigned)mine);
    }
    float fx = (float)(g >> 13) * (8000.0f / 127.0f) - 4000.0f;
    float fy = (float)((g >> 6) & 127u) * (8000.0f / 127.0f) - 4000.0f;
    float fz = (float)(g & 63u) * (2000.0f / 63.0f) - 700.0f;
    float conf = (val > 0.3f) ? 0.0f : -1.0f;
    float* o = out + ((size_t)b * NK + lane) * 5;
    o[0] = fx; o[1] = fy; o[2] = fz; o[3] = conf; o[4] = val;
  }
}

extern "C" void kernel_launch(void* const* d_in, const int* in_sizes, int n_in,
                              void* d_out, int out_size, void* d_ws, size_t ws_size,
                              hipStream_t stream) {
  const float* in = (const float*)d_in[0];
  float* out = (float*)d_out;
  u64* part = (u64*)d_ws;  // 102,400 B used

  const int B = in_sizes[0] >> 20;  // 128*128*64 = 2^20 elements per batch
  dim3 gridA(TY, 4, (unsigned)B);
  peaks_topk<<<gridA, dim3(TPB), 0, stream>>>(in, part);
  final_select<<<dim3((unsigned)B), dim3(64), 0, stream>>>(part, out);
}

// Round 3
// 218.290 us; speedup vs baseline: 1.5764x; 1.0186x over previous
//
#include <hip/hip_runtime.h>
#include <stdint.h>

// ProposalLayerSoft: 3x3x3 NMS + per-batch top-10 + coord epilogue.
// Input:  d_in[0] = root_cubes f32 [B=32, X=128, Y=128, Z=64]
// Output: d_out   = f32 [B, 10, 5] = (x,y,z, valid-1, score)
// ws: 32*40*10*8 = 102,400 bytes of per-block top-10 keys.
//
// 8-z-per-lane slab under __launch_bounds__(256,5) (cap 48 VGPR), WITH
// 1-plane prefetch. History/model:
//   r0: 16-z + prefetch, bound4 -> VGPR 60, capacity 4 -> two phases,
//       occ 29%, 78us.  r1: bound6 -> 40-cap, 580MB scratch, 210us.
//   r2: 8-z no-prefetch, bound5 -> VGPR 32, occ 41%, but load->use
//       latency exposed every t-iter: per-wave issue duty fell 15%->10%
//       and dur stayed 82us. Makespan model (work/concurrency, no pipe
//       saturated) held across r0/r2.
// THIS ROUND: spend r2's 16 spare VGPRs on vT[8]+lT/hT prefetch: issue
// loads for plane x+2 at iter top, consume x+1 (loaded last iter). One
// full j-loop (~300cy) + 5-wave TLP covers HBM latency. Carried state:
// pm/zmLast/vC/vN/vT = 40 f32 + 2 halos -> ~44 VGPR, fits cap 48 with
// capacity 5 -> 1280 blocks = exactly 5/CU, single phase.
// DO NOT raise min_waves past 5 (r1: cap 40 spills). DO NOT drop
// prefetch (r2: latency-bound). 16-z needs 64 carried -> can't fit 48.
//   z: in-register max3; stripe bounds via lane+-16 shuffles; cross-wave
//      halo (z=31/32) via 2 clamped scalar loads per plane (prefetched).
//   y: v_mov_dpp row_shl/shr:1.
//   x: rolled 16-step sweep, 3-array rotation vC<-vN<-vT.
// Peaks: ballot+mbcnt compacted append to per-wave LDS list (no atomics).

#define TPB 256
#define NK 10
#define TY 10                    // y tiles, 14 interior columns each
#define BLOCKS_PER_B (4 * TY)    // grid.y=4 packs x 10 ty = 40
#define WCAP 512                 // per-wave cand cap (mean ~265 = 1/27 of 7168)
typedef unsigned long long u64;

__device__ __forceinline__ u64 bfly_max_u64(u64 v) {
#pragma unroll
  for (int off = 1; off < 64; off <<= 1) {
    u64 o = __shfl_xor(v, off, 64);
    v = (o > v) ? o : v;
  }
  return v;
}

// DPP row shifts within 16-lane rows; bound_ctrl=1 -> 0.0f fill at row
// edges (only yi=0/15 halo lanes, never emitted).
__device__ __forceinline__ float dpp_nbr_a(float v) {  // one y-neighbor
  return __int_as_float(__builtin_amdgcn_update_dpp(
      0, __float_as_int(v), 0x101, 0xF, 0xF, true));   // row_shl:1
}
__device__ __forceinline__ float dpp_nbr_b(float v) {  // other y-neighbor
  return __int_as_float(__builtin_amdgcn_update_dpp(
      0, __float_as_int(v), 0x111, 0xF, 0xF, true));   // row_shr:1
}

__global__ __launch_bounds__(TPB, 5) void peaks_topk(
    const float* __restrict__ in, u64* __restrict__ part) {
  __shared__ u64 cand[4][WCAP];  // 16 KB
  __shared__ u64 wtop[4 * NK];
  const int tid = threadIdx.x;
  const int w = tid >> 6, lane = tid & 63;
  const int yi = lane & 15, zq = lane >> 4;
  const int ty = blockIdx.x, b = blockIdx.z;
  const int seg = blockIdx.y * 2 + (w >> 1);  // 0..7, 16 x-steps each
  const int zh = w & 1;                       // z half: 0 -> z 0..31, 1 -> 32..63
  const int y0 = ty * 14 - 1;
  const int gy = y0 + yi;
  const int cy = min(127, max(0, gy));        // clamp == dup col: max-safe
  const int x0 = seg << 4;
  const bool emit_ok = (yi >= 1) && (yi <= 14) && (gy <= 127);
  const int zoff = zh * 32 + (zq << 3);       // lane's z base in column
  const int zlo = max(0, zoff - 1);           // cross-wave z halo offsets
  const int zhi = min(63, zoff + 8);          // (clamped: OOB -> -inf select)
  const bool lo_inf = (zq == 0) && (zh == 0); // z = -1
  const bool hi_inf = (zq == 3) && (zh == 1); // z = 64
  const float* __restrict__ py = in + ((size_t)b << 20) + ((size_t)cy << 6);

  int wcnt = 0;  // wave-uniform candidate count (scalar)
  float pm[8], zmLast[8], vC[8], vN[8], vT[8];
  float lN, hN, lT, hT;

  auto loadv = [&](int x, float* v, float& lo, float& hi) {
    const int cx = min(127, max(0, x));       // x clamp = dup plane: max-safe
    const float* p = py + ((size_t)cx << 13);
    float4 a = *(const float4*)(p + zoff);
    float4 bb = *(const float4*)(p + zoff + 4);
    v[0] = a.x;  v[1] = a.y;  v[2] = a.z;  v[3] = a.w;
    v[4] = bb.x; v[5] = bb.y; v[6] = bb.z; v[7] = bb.w;
    lo = p[zlo];                              // used by zq==0 lanes
    hi = p[zhi];                              // used by zq==3 lanes
  };
  // z-stage max3 over 8-elem stripe; stripe bounds: lane+-16 shuffles for
  // in-wave quads, loaded halo scalar (or -inf at volume edge) otherwise.
  auto zmcalc = [&](const float* v, float lo, float hi, float* zm) {
    float vl = __shfl_up(v[7], 16, 64);
    float vr = __shfl_down(v[0], 16, 64);
    vl = (zq == 0) ? (lo_inf ? -1e30f : lo) : vl;
    vr = (zq == 3) ? (hi_inf ? -1e30f : hi) : vr;
    zm[0] = fmaxf(vl, fmaxf(v[0], v[1]));
#pragma unroll
    for (int j = 1; j < 7; ++j)
      zm[j] = fmaxf(v[j - 1], fmaxf(v[j], v[j + 1]));
    zm[7] = fmaxf(v[6], fmaxf(v[7], vr));
  };

  // Prologue: pm = max(zm(x0-1), zm(x0)); zmLast = zm(x0); vC = v(x0);
  //           vN = v(x0+1) prefetched with its halos.
  {
    float t0, t1;
    loadv(x0 - 1, vN, t0, t1);
    zmcalc(vN, t0, t1, pm);        // pm holds zm(x0-1) temporarily
    loadv(x0, vC, t0, t1);
    zmcalc(vC, t0, t1, zmLast);    // zm(x0)
#pragma unroll
    for (int j = 0; j < 8; ++j) pm[j] = fmaxf(pm[j], zmLast[j]);
    loadv(x0 + 1, vN, lN, hN);
  }

#pragma unroll 1
  for (int t = 0; t < 16; ++t) {
    const int x = x0 + t;
    loadv(x + 2, vT, lT, hT);      // prefetch plane x+2 (clamp: tail-safe)
    float vl = __shfl_up(vN[7], 16, 64);
    float vr = __shfl_down(vN[0], 16, 64);
    vl = (zq == 0) ? (lo_inf ? -1e30f : lN) : vl;
    vr = (zq == 3) ? (hi_inf ? -1e30f : hN) : vr;
#pragma unroll
    for (int j = 0; j < 8; ++j) {  // fused zm + rotate + emit (min live set)
      float a = (j == 0) ? vl : vN[j - 1];
      float c = (j == 7) ? vr : vN[j + 1];
      float zmn = fmaxf(a, fmaxf(vN[j], c));      // zm(x+1)[j]
      float xm = fmaxf(pm[j], zmn);               // max over 3 x-planes
      pm[j] = fmaxf(zmLast[j], zmn);              // rotate in place
      zmLast[j] = zmn;
      float l = dpp_nbr_a(xm);                    // y-neighbors via DPP
      float r = dpp_nbr_b(xm);
      float m27 = fmaxf(xm, fmaxf(l, r));
      float v = vC[j];
      const bool pred = emit_ok && (v >= m27);    // v == 27-max (self-incl.)
      u64 mask = __ballot(pred);
      if (pred) {
        unsigned g = ((unsigned)x << 13) | ((unsigned)gy << 6) |
                     (unsigned)(zoff + j);
        u64 key = ((u64)__float_as_uint(v) << 32) | (u64)(unsigned)(~g);
        int ofs = __builtin_amdgcn_mbcnt_hi(
            (unsigned)(mask >> 32),
            __builtin_amdgcn_mbcnt_lo((unsigned)mask, 0));
        int slot = wcnt + ofs;
        if (slot < WCAP) cand[w][slot] = key;
      }
      wcnt += (int)__popcll(mask);
    }
#pragma unroll
    for (int j = 0; j < 8; ++j) {  // rotate planes (vT wait lands here)
      vC[j] = vN[j];
      vN[j] = vT[j];
    }
    lN = lT; hN = hT;
  }

  // ---- wave top-10 from LDS list (regs + butterfly, no barriers) ----
  __builtin_amdgcn_s_waitcnt(0);  // drain own-wave LDS writes
  const int count = min(wcnt, WCAP);
  u64 c[WCAP / 64];
#pragma unroll
  for (int i = 0; i < WCAP / 64; ++i) {
    int idx = lane + (i << 6);
    c[i] = (idx < count) ? cand[w][idx] : 0;
  }
  u64 mine = 0;
#pragma unroll 1
  for (int r = 0; r < NK; ++r) {
    u64 best = c[0];
#pragma unroll
    for (int i = 1; i < WCAP / 64; ++i) best = (c[i] > best) ? c[i] : best;
    u64 m = bfly_max_u64(best);
    if (m != 0 && best == m) {  // unique keys: only owner lane matches
#pragma unroll
      for (int i = 0; i < WCAP / 64; ++i)
        if (c[i] == m) c[i] = 0;
    }
    if (lane == r) mine = m;
  }
  if (lane < NK) wtop[w * NK + lane] = mine;
  __syncthreads();

  // ---- block merge 40 -> 10 (wave 0), one barrier total ----
  if (w == 0) {
    u64 c0 = (lane < 4 * NK) ? wtop[lane] : 0;
    u64 mv = 0;
#pragma unroll 1
    for (int r = 0; r < NK; ++r) {
      u64 m = bfly_max_u64(c0);
      if (m != 0 && c0 == m) c0 = 0;
      if (lane == r) mv = m;
    }
    if (lane < NK) {
      const int bi = blockIdx.y * TY + ty;  // 0..39 within batch
      part[((size_t)b * BLOCKS_PER_B + bi) * NK + lane] = mv;
    }
  }
}

// One wave per batch: 400 keys -> 7 regs/lane -> 10 butterfly rounds.
// Zero barriers, zero LDS.
__global__ __launch_bounds__(64) void final_select(
    const u64* __restrict__ part, float* __restrict__ out) {
  const int lane = threadIdx.x & 63;
  const int b = blockIdx.x;
  const int NKEY = BLOCKS_PER_B * NK;  // 400

  const u64* __restrict__ src = part + (size_t)b * NKEY;
  u64 c[7];
#pragma unroll
  for (int i = 0; i < 7; ++i) {
    int idx = lane + (i << 6);
    c[i] = (idx < NKEY) ? src[idx] : 0;
  }
  u64 mine = 0;
#pragma unroll 1
  for (int r = 0; r < NK; ++r) {
    u64 best = c[0];
#pragma unroll
    for (int i = 1; i < 7; ++i) best = (c[i] > best) ? c[i] : best;
    u64 m = bfly_max_u64(best);
    if (m != 0 && best == m) {
#pragma unroll
      for (int i = 0; i < 7; ++i)
        if (c[i] == m) c[i] = 0;
    }
    if (lane == r) mine = m;
  }
  if (lane < NK) {
    float val = 0.0f;
    unsigned g = 0u;
    if (mine != 0) {
      val = __uint_as_float((unsigned)(mine >> 32));
      g = ~((unsigned)mine);
    }
    float fx = (float)(g >> 13) * (8000.0f / 127.0f) - 4000.0f;
    float fy = (float)((g >> 6) & 127u) * (8000.0f / 127.0f) - 4000.0f;
    float fz = (float)(g & 63u) * (2000.0f / 63.0f) - 700.0f;
    float conf = (val > 0.3f) ? 0.0f : -1.0f;
    float* o = out + ((size_t)b * NK + lane) * 5;
    o[0] = fx; o[1] = fy; o[2] = fz; o[3] = conf; o[4] = val;
  }
}

extern "C" void kernel_launch(void* const* d_in, const int* in_sizes, int n_in,
                              void* d_out, int out_size, void* d_ws, size_t ws_size,
                              hipStream_t stream) {
  const float* in = (const float*)d_in[0];
  float* out = (float*)d_out;
  u64* part = (u64*)d_ws;  // 102,400 B used

  const int B = in_sizes[0] >> 20;  // 128*128*64 = 2^20 elements per batch
  dim3 gridA(TY, 4, (unsigned)B);
  peaks_topk<<<gridA, dim3(TPB), 0, stream>>>(in, part);
  final_select<<<dim3((unsigned)B), dim3(64), 0, stream>>>(part, out);
}